// Round 10
// baseline (379.038 us; speedup 1.0000x reference)
//
#include <hip/hip_runtime.h>
#include <stdint.h>

// LocalCorrelation on MI355X (gfx950).  R16 = R15 with the MFMA intrinsic
// name fixed: legacy K=16 builtin is __builtin_amdgcn_mfma_f32_16x16x16f16
// (NO underscore before f16; only the gfx950-new K=32 shapes have it).
// Everything else verbatim from R15 -- its theory is still untested.
//
// R15 design: fused kernel re-based on DMA staging (global_load_lds),
// fp32-in-LDS, K=16 MFMA x 16 phases.  R13/R14 law: register-staged prefetch
// + 64-reg acc ALWAYS spills (254 MB / 134 MB scratch) -> staging must use
// the zero-VGPR DMA path.  fp16 can't convert in-flight -> stage fp32,
// convert in the frag read (VALU has headroom).  2x32 KB buffers (512 px x
// 16 c fp32), T3-minimal pipeline: issue DMA(ph+1) at phase top, ONE
// s_waitcnt vmcnt(0) + raw s_barrier at phase end.
// OOB b-px: DMA source clamped, inv_b=0 in epilogue (reference value for an
// OOB shift is exactly 0 = garbage*0) -> no zero pass at all.
// Swizzle: LDS row px holds c-chunk (ch ^ (px&3)) at slot ch; folded into
// the per-lane precomputed DMA offsets; frag reads use chunk q^(ml&3)
// (row&3 == ml&3 for both A and B rows).  Sumsq: thread t owns px t, reads
// chunks in (k+t)&3 order (order-agnostic, bank-spread).
// Epilogue/acc mapping byte-identical to R12 (C/D layout is shape-determined;
// 16x16x16 == 16x16x32 mapping).

typedef _Float16 half4v __attribute__((ext_vector_type(4)));
typedef float floatx4 __attribute__((ext_vector_type(4)));

#define B_ 4
#define C_ 256
#define H_ 128
#define W_ 128
#define K2_ 169
#define INV_T 14.285714285714286f
#define HW_ (H_ * W_)  // 16384
#define CPP 16         // channels per phase
#define NPH 16         // phases (16 x 16 = 256 c)

// LDS: stage[2][512 px][16 c] fp32 = 2 x 32 KB; ostage (22984 B) overlays buf0.
union SmemU { float stage[2][512 * CPP]; float ostage[K2_ * 2 * 17]; };

static __device__ __forceinline__ void dma4(const float* g, float* l) {
  __builtin_amdgcn_global_load_lds((const __attribute__((address_space(1))) void*)g,
                                   (__attribute__((address_space(3))) void*)l, 4, 0, 0);
}

#define ISSUE_DMA(PH, NB)                                                      \
  do {                                                                         \
    float* db_ = u.stage[NB] + wv * 64 * CPP;  /* wave-uniform dest base */    \
    const float* pb_ = base + (size_t)(PH) * CPP * HW_;                        \
    _Pragma("unroll") for (int i_ = 0; i_ < 16; ++i_)                          \
      dma4(pb_ + off[i_], db_ + i_ * 64);                                      \
  } while (0)

#define PHASE_BARRIER()                                                        \
  do {                                                                         \
    asm volatile("s_waitcnt vmcnt(0)" ::: "memory");                           \
    __builtin_amdgcn_sched_barrier(0);                                         \
    __builtin_amdgcn_s_barrier();                                              \
    __builtin_amdgcn_sched_barrier(0);                                         \
  } while (0)

__global__ __launch_bounds__(512, 4) void corr_fused(const float* __restrict__ fa,
                                                     const float* __restrict__ fb,
                                                     float* __restrict__ out) {
  __shared__ SmemU u;
  __shared__ float inv_b[448];
  __shared__ float inv_a[64];
  const int bid = blockIdx.x;
  const int xcd = bid & 7, l = bid >> 3;  // XCD-contiguous h-bands (halo L2 reuse)
  const int bb = l >> 5, hseg = (l >> 3) & 3, wt = l & 7;
  const int hg = xcd * 4 + hseg;
  const int h0 = hg * 4, w0 = wt * 16;
  const int t = threadIdx.x;
  const int lane = t & 63, wv = t >> 6;  // 8 waves
  const int ml = lane & 15, q = lane >> 4;
  const int ntile = wv & 1, jjg = wv >> 1;

  // ---- per-lane DMA source precompute ----
  // dest float (rel. to wave base) = i*64 + lane  ==  px = wv*64+i*4+(lane>>4),
  // slot f = lane&15.  Slot (px, f): chunk=f>>2, pos=f&3 holds
  // c_local = ((f>>2) ^ (px&3))*4 + pos; px&3 == lane>>4 (indep. of i).
  const int csl = ((((lane & 15) >> 2) ^ (lane >> 4)) << 2) + (lane & 3);
  const float* srcw = (wv == 7) ? fa : fb;  // waves 0-6: 448 b-px; wave 7: 64 a-px
  const float* base = srcw + (size_t)bb * C_ * HW_ + (size_t)csl * HW_;
  int off[16];
  #pragma unroll
  for (int i = 0; i < 16; ++i) {
    const int px = wv * 64 + i * 4 + (lane >> 4);
    int io;
    if (px < 448) {  // b-halo: 16 rows x 28 cols
      const int row = px / 28, col = px - row * 28;
      const int rim = h0 - 6 + row, cim = w0 - 6 + col;
      const bool okp = ((unsigned)rim < (unsigned)H_) && ((unsigned)cim < (unsigned)W_);
      io = okp ? (rim * W_ + cim) : 0;  // OOB: clamp (inv_b=0 kills the value)
    } else {         // a-tile: 4 rows x 16 cols
      const int ap = px - 448;
      io = (h0 + (ap >> 4)) * W_ + (w0 + (ap & 15));
    }
    off[i] = io;
  }

  // is THIS thread's own px (px = t) OOB?  (for inv_b)
  bool own_ok = true;
  if (t < 448) {
    const int row = t / 28, col = t - row * 28;
    const int rim = h0 - 6 + row, cim = w0 - 6 + col;
    own_ok = ((unsigned)rim < (unsigned)H_) && ((unsigned)cim < (unsigned)W_);
  }

  // ---- prologue: stage phase 0 into buf0 ----
  ISSUE_DMA(0, 0);
  PHASE_BARRIER();

  floatx4 acc[4][4] = {};  // [uu: jj=jjg+4uu][r]; 13 of 16 valid per wave
  float ss = 0.f;          // fp32 sumsq of own px (full precision)

  for (int ph = 0; ph < NPH; ++ph) {
    if (ph < NPH - 1) ISSUE_DMA(ph + 1, (ph + 1) & 1);  // lands under this phase

    const float* sb = u.stage[ph & 1];

    // A-frags: row = 448 + r*16 + ml; chunk q^(ml&3) holds c_local q*4..q*4+3
    half4v A[4];
    #pragma unroll
    for (int r = 0; r < 4; ++r) {
      const floatx4 f =
          *(const floatx4*)(sb + (448 + r * 16 + ml) * CPP + ((q ^ (ml & 3)) << 2));
      A[r] = half4v{(_Float16)f.x, (_Float16)f.y, (_Float16)f.z, (_Float16)f.w};
    }

    #pragma unroll
    for (int uu = 0; uu < 4; ++uu) {
      const int jj = jjg + 4 * uu;
      const int brow = jj * 28 + ntile * 16 + ml;  // brow&3 == ml&3
      const floatx4 f =
          *(const floatx4*)(sb + brow * CPP + ((q ^ (ml & 3)) << 2));
      const half4v Bf = half4v{(_Float16)f.x, (_Float16)f.y, (_Float16)f.z, (_Float16)f.w};
      #pragma unroll
      for (int r = 0; r < 4; ++r) {
        if ((uu == 0 && r > jjg) || (uu == 3 && r < jjg)) continue;  // dy out of band
        acc[uu][r] = __builtin_amdgcn_mfma_f32_16x16x16f16(A[r], Bf, acc[uu][r], 0, 0, 0);
      }
    }

    // sumsq of own px: all 4 chunks, bank-rotated order (order-agnostic sum)
    #pragma unroll
    for (int k = 0; k < 4; ++k) {
      const floatx4 f = *(const floatx4*)(sb + t * CPP + (((k + t) & 3) << 2));
      ss += f.x * f.x + f.y * f.y + f.z * f.z + f.w * f.w;
    }

    if (ph < NPH - 1) PHASE_BARRIER();
  }

  // ---- inverse norms (OOB b-px: inv_b = 0 -> output exactly 0) ----
  if (t < 448) inv_b[t] = own_ok ? (1.0f / fmaxf(sqrtf(ss), 1e-12f)) : 0.f;
  else         inv_a[t - 448] = INV_T / fmaxf(sqrtf(ss), 1e-12f);
  __syncthreads();  // drains everything; fences buf0 for ostage overlay

  // ---- epilogue: scale by inv-norms; 2 rounds of 2 rows; ostage overlays buf0 ----
  #pragma unroll
  for (int r2 = 0; r2 < 2; ++r2) {
    if (r2) __syncthreads();
    #pragma unroll
    for (int uu = 0; uu < 4; ++uu) {
      const int jj = jjg + 4 * uu;
      const int col = ntile * 16 + ml;
      const float sbv = (col < 28) ? inv_b[jj * 28 + col] : 0.f;  // col>=28 is garbage
      #pragma unroll
      for (int rr = 2 * r2; rr < 2 * r2 + 2; ++rr) {
        if ((uu == 0 && rr > jjg) || (uu == 3 && rr < jjg)) continue;
        const int dy6 = jj - rr;  // in [0,12]
        #pragma unroll
        for (int p = 0; p < 4; ++p) {
          const int ip = q * 4 + p;
          const int dx6 = col - ip;
          if (dx6 >= 0 && dx6 <= 12)
            u.ostage[((dy6 * 13 + dx6) * 2 + (rr & 1)) * 17 + ip] =
                acc[uu][rr][p] * sbv * inv_a[rr * 16 + ip];
        }
      }
    }
    __syncthreads();
    for (int s = t; s < K2_ * 32; s += 512) {
      const int k = s >> 5, r1 = (s >> 4) & 1, ip = s & 15;
      out[(((size_t)bb * K2_ + k) * H_ + h0 + 2 * r2 + r1) * W_ + w0 + ip] =
          u.ostage[(k * 2 + r1) * 17 + ip];
    }
  }
}

extern "C" void kernel_launch(void* const* d_in, const int* in_sizes, int n_in,
                              void* d_out, int out_size, void* d_ws, size_t ws_size,
                              hipStream_t stream) {
  const float* fa = (const float*)d_in[0];
  const float* fb = (const float*)d_in[1];
  float* out = (float*)d_out;
  (void)d_ws; (void)ws_size;  // workspace not needed
  corr_fused<<<1024, 512, 0, stream>>>(fa, fb, out);
}